// Round 2
// baseline (234.016 us; speedup 1.0000x reference)
//
#include <hip/hip_runtime.h>

// Wavelet analysis(stride2)+synthesis(transposed) fused into two 18-tap
// polyphase FIRs applied directly to the input:
//   even p: ya[p] = sum_d We[d]*sig_m[p+d-8]
//   odd  p: ya[p] = sum_d Wo[d]*sig_m[p+d-9]
//
// v2: no LDS (direct coalesced float4 global loads; L1/L2 absorb the 5x
// window overlap) and v_pk_fma_f32 packed fp32: each thread computes TWO
// 4-output windows (A at q, B at q+1024) so every FMA is a float2 op
// acc += coef * (wA[i], wB[i]) -> v_pk_fma_f32, halving VALU issue.

typedef float f2 __attribute__((ext_vector_type(2)));

#define L_SIG 524288
#define SPAN  2048          // outputs covered per block (256 thr * 8)
#define HALF  1024

constexpr float RL[10] = {
    0.160102397974125f,   0.6038292697974729f,  0.7243085284385744f,
    0.13842814590110342f, -0.24229488706619015f, -0.03224486958502952f,
    0.07757149384006515f, -0.006241490213011705f, -0.012580751999015526f,
    0.003335725285001549f};

struct Coef { float we[18]; float wo[18]; };

constexpr Coef make_coef() {
    Coef c{};
    for (int d = 0; d < 18; ++d) {
        float se = 0.f, so = 0.f;
        for (int j = 0; j < 5; ++j) {
            int i = d - 2 * j;               // REC_LO tap index
            if (i >= 0 && i < 10) {
                se += RL[8 - 2 * j] * RL[i]; // DEC_LO[2j+1] = RL[8-2j]
                so += RL[9 - 2 * j] * RL[i]; // DEC_LO[2j]   = RL[9-2j]
            }
        }
        c.we[d] = se;
        c.wo[d] = so;
    }
    return c;
}

constexpr Coef CF = make_coef();

__global__ __launch_bounds__(256)
void wavelet_pk_kernel(const float* __restrict__ x, float* __restrict__ out) {
    const int batch = blockIdx.y;
    const int p0    = blockIdx.x * SPAN;
    const float* xb = x   + (size_t)batch * L_SIG;
    float*       ob = out + (size_t)batch * L_SIG;

    const int t  = threadIdx.x;
    const int qA = p0 + 4 * t;          // outputs qA..qA+3  (qA even)
    const int qB = qA + HALF;           // outputs qB..qB+3

    float wA[20], wB[20];

    const bool edge = (blockIdx.x == 0) || (blockIdx.x == gridDim.x - 1);
    if (edge) {
        // Scalar loads with symmetric-mirror mapping (2 blocks per row).
#pragma unroll
        for (int i = 0; i < 20; ++i) {
            int ka = qA + i - 8;
            int kb = qB + i - 8;
            ka = (ka < 0) ? (-1 - ka) : ((ka >= L_SIG) ? (2 * L_SIG - 1 - ka) : ka);
            kb = (kb < 0) ? (-1 - kb) : ((kb >= L_SIG) ? (2 * L_SIG - 1 - kb) : kb);
            wA[i] = xb[ka];
            wB[i] = xb[kb];
        }
    } else {
        // Interior: 16B-aligned (qA-8 multiple of 4), perfectly coalesced.
        const float4* a4 = (const float4*)(xb + qA - 8);
        const float4* b4 = (const float4*)(xb + qB - 8);
#pragma unroll
        for (int r = 0; r < 5; ++r) {
            float4 fa = a4[r];
            float4 fb = b4[r];
            wA[4 * r + 0] = fa.x; wA[4 * r + 1] = fa.y;
            wA[4 * r + 2] = fa.z; wA[4 * r + 3] = fa.w;
            wB[4 * r + 0] = fb.x; wB[4 * r + 1] = fb.y;
            wB[4 * r + 2] = fb.z; wB[4 * r + 3] = fb.w;
        }
    }

    // Pack the two windows lane-wise: u[i] = (wA[i], wB[i]).
    f2 u[20];
#pragma unroll
    for (int i = 0; i < 20; ++i) {
        f2 p; p[0] = wA[i]; p[1] = wB[i];
        u[i] = p;
    }

    f2 e0 = 0.f, d1 = 0.f, e2 = 0.f, d3 = 0.f;
#pragma unroll
    for (int d = 0; d < 18; ++d) {
        e0 += CF.we[d] * u[d];       // even outputs qA,   qB
        d1 += CF.wo[d] * u[d];       // odd  outputs qA+1, qB+1
        e2 += CF.we[d] * u[d + 2];   // even outputs qA+2, qB+2
        d3 += CF.wo[d] * u[d + 2];   // odd  outputs qA+3, qB+3
    }

    float4 oa = make_float4(e0[0], d1[0], e2[0], d3[0]);
    float4 obv = make_float4(e0[1], d1[1], e2[1], d3[1]);
    *((float4*)(ob + qA)) = oa;
    *((float4*)(ob + qB)) = obv;
}

extern "C" void kernel_launch(void* const* d_in, const int* in_sizes, int n_in,
                              void* d_out, int out_size, void* d_ws, size_t ws_size,
                              hipStream_t stream) {
    const float* x = (const float*)d_in[0];
    float* out     = (float*)d_out;

    const int B = in_sizes[0] / L_SIG;        // 64
    dim3 grid(L_SIG / SPAN, B);               // (256, 64)
    wavelet_pk_kernel<<<grid, 256, 0, stream>>>(x, out);
}